// Round 1
// baseline (7369.682 us; speedup 1.0000x reference)
//
#include <hip/hip_runtime.h>
#include <hip/hip_cooperative_groups.h>

typedef _Float16 f16;
typedef _Float16 f16x4 __attribute__((ext_vector_type(4)));
typedef _Float16 f16x8 __attribute__((ext_vector_type(8)));
typedef float    f32x4 __attribute__((ext_vector_type(4)));

#define S_   5
#define B_   32
#define T_   25
#define TM   24            // T-1 steps per sentence
#define H_   1024
#define E_   512
#define V_   32000
#define G3   (3*H_)        // 3072
#define M_ALL (S_*TM*B_)   // 3840 rows, ordered m = (s*TM + t)*B_ + b

// ---------------- fp32 -> fp16 convert (vectorized) ----------------
__global__ __launch_bounds__(256) void k_cvt(const float* __restrict__ src,
                                             f16* __restrict__ dst, int n4) {
  int i = blockIdx.x * 256 + threadIdx.x;
  if (i >= n4) return;
  float4 v = ((const float4*)src)[i];
  f16x4 o = {(f16)v.x, (f16)v.y, (f16)v.z, (f16)v.w};
  ((f16x4*)dst)[i] = o;
}

// ---------------- embed gather -> x16 (m-major = (s,t,b)) ----------------
__global__ __launch_bounds__(128) void k_gather(const int* __restrict__ ids,
                                                const float* __restrict__ embed,
                                                f16* __restrict__ x) {
  int m = blockIdx.x;                       // 0..3839
  int s = m / (TM * B_);
  int r = m % (TM * B_);
  int t = r >> 5, b = r & 31;
  int tok = ids[(s * B_ + b) * T_ + t];     // tokens[:, :-1]
  const float4* src = (const float4*)(embed + (size_t)tok * E_);
  f16x4* dst = (f16x4*)(x + (size_t)m * E_);
  int i = threadIdx.x;                      // 128 threads * 4 = 512 = E_
  float4 v = src[i];
  dst[i] = (f16x4){(f16)v.x, (f16)v.y, (f16)v.z, (f16)v.w};
}

// ---------------- TN GEMM: C[m][n] = sum_k A[m][k]*B[n][k] (+bias[n]) ----------------
// A: (M,K) f16 row-major, B: (N,K) f16 row-major, C fp32.
// remap=1: m=(s*TM+t)*B_+b is scattered to C[((s*B_+b)*TM+t)*N + n]  (logits layout)
__global__ __launch_bounds__(256) void k_gemm(const f16* __restrict__ A,
                                              const f16* __restrict__ B,
                                              const float* __restrict__ bias,
                                              float* __restrict__ C,
                                              int K, int N, int remap) {
  __shared__ __align__(16) f16 sA[128][40];   // +8 pad: 2-way max bank aliasing
  __shared__ __align__(16) f16 sB[128][40];
  const int m0 = blockIdx.x * 128, n0 = blockIdx.y * 128;
  const int tid = threadIdx.x, wave = tid >> 6, lane = tid & 63;
  const int l16 = lane & 15, lq = lane >> 4;
  const int wr = (wave & 1) * 64, wc = (wave >> 1) * 64;
  const int rS = tid >> 2, cS = (tid & 3) * 8;
  f32x4 acc[4][4] = {};
  for (int k0 = 0; k0 < K; k0 += 32) {
    *(f16x8*)&sA[rS][cS]    = *(const f16x8*)&A[(size_t)(m0 + rS) * K + k0 + cS];
    *(f16x8*)&sA[rS + 64][cS] = *(const f16x8*)&A[(size_t)(m0 + rS + 64) * K + k0 + cS];
    *(f16x8*)&sB[rS][cS]    = *(const f16x8*)&B[(size_t)(n0 + rS) * K + k0 + cS];
    *(f16x8*)&sB[rS + 64][cS] = *(const f16x8*)&B[(size_t)(n0 + rS + 64) * K + k0 + cS];
    __syncthreads();
    f16x8 af[4], bf[4];
#pragma unroll
    for (int i = 0; i < 4; ++i) af[i] = *(const f16x8*)&sA[wr + i * 16 + l16][lq * 8];
#pragma unroll
    for (int j = 0; j < 4; ++j) bf[j] = *(const f16x8*)&sB[wc + j * 16 + l16][lq * 8];
#pragma unroll
    for (int i = 0; i < 4; ++i)
#pragma unroll
      for (int j = 0; j < 4; ++j)
        acc[i][j] = __builtin_amdgcn_mfma_f32_16x16x32_f16(af[i], bf[j], acc[i][j], 0, 0, 0);
    __syncthreads();
  }
#pragma unroll
  for (int i = 0; i < 4; ++i)
#pragma unroll
    for (int j = 0; j < 4; ++j)
#pragma unroll
      for (int e = 0; e < 4; ++e) {
        int rm = m0 + wr + i * 16 + lq * 4 + e;   // C/D: row=(lane>>4)*4+e, col=lane&15
        int cn = n0 + wc + j * 16 + l16;
        float v = acc[i][j][e];
        if (bias) v += bias[cn];
        size_t off;
        if (remap) {
          int s = rm / (TM * B_), rr = rm % (TM * B_), t = rr >> 5, b = rr & 31;
          off = (size_t)((s * B_ + b) * TM + t) * N + cn;
        } else {
          off = (size_t)rm * N + cn;
        }
        C[off] = v;
      }
}

// ---------------- persistent GRU layer recurrence (cooperative) ----------------
// 32 blocks x 256 threads. Block owns 32 hidden cols; wave w: rows (w>>1)*16..+16,
// cols (w&1)*16..+16, all 3 gates (combine stays in-register).
// Ping-pong: h buffers by global-step parity, carry buffers by sentence parity.
__global__ __launch_bounds__(256) void k_rec(const f16* __restrict__ Whh,   // (3H,H) f16
                                             const float* __restrict__ bhh, // (3H)
                                             const float* __restrict__ gi,  // (M_ALL,3H) incl b_ih
                                             const int* __restrict__ lens,  // (S,B)
                                             float* h32a, float* h32b,
                                             f16* h16a, f16* h16b,
                                             float* c32a, float* c32b,
                                             f16* c16a, f16* c16b,
                                             f16* __restrict__ hall) {      // (M_ALL,H)
  __shared__ __align__(16) f16 sh[B_][H_ + 8];
  cooperative_groups::grid_group grid = cooperative_groups::this_grid();
  const int blk = blockIdx.x, tid = threadIdx.x;
  const int wave = tid >> 6, lane = tid & 63;
  const int l16 = lane & 15, lq = lane >> 4;
  const int rh = (wave >> 1) * 16, ch = (wave & 1) * 16;
  const int col = blk * 32 + ch + l16;        // == this lane's D-col AND B-frag row
  const float b_r = bhh[col], b_z = bhh[H_ + col], b_n = bhh[2 * H_ + col];
  const f16* wR = Whh + (size_t)col * H_ + lq * 8;
  const f16* wZ = Whh + (size_t)(H_ + col) * H_ + lq * 8;
  const f16* wN = Whh + (size_t)(2 * H_ + col) * H_ + lq * 8;
  int g = 0;
  for (int s = 0; s < S_; ++s) {
    for (int t = 0; t < TM; ++t, ++g) {
      const f16*  hsrc   = (t == 0) ? ((s & 1) ? c16b : c16a)
                                    : ((g & 1) ? h16b : h16a);
      const float* hold32 = (t == 0) ? ((s & 1) ? c32b : c32a)
                                     : ((g & 1) ? h32b : h32a);
      f16*   h16w = (((g + 1) & 1) ? h16b : h16a);
      float* h32w = (((g + 1) & 1) ? h32b : h32a);
      f16*   c16w = (((s + 1) & 1) ? c16b : c16a);
      float* c32w = (((s + 1) & 1) ? c32b : c32a);
      // stage h (32 x 1024 f16) into LDS
      for (int i = tid; i < B_ * (H_ / 8); i += 256) {
        int r = i >> 7, c = (i & 127) * 8;
        *(f16x8*)&sh[r][c] = *(const f16x8*)&hsrc[r * H_ + c];
      }
      __syncthreads();
      const int mbase = g * B_;
      // prefetch gi + h_old (independent of h matmul) so loads overlap MFMA
      float gir[4], giz[4], gin[4], hprev[4];
#pragma unroll
      for (int e = 0; e < 4; ++e) {
        int row = rh + lq * 4 + e;
        size_t gx = (size_t)(mbase + row) * G3 + col;
        gir[e] = gi[gx];
        giz[e] = gi[gx + H_];
        gin[e] = gi[gx + 2 * H_];
        hprev[e] = hold32[row * H_ + col];
      }
      f32x4 ar = {}, az = {}, an = {};
      const f16* aP = &sh[rh + l16][lq * 8];  // A-frag: m=lane&15, k=quad*8+j
#pragma unroll 4
      for (int kc = 0; kc < H_ / 32; ++kc) {
        f16x8 a = *(const f16x8*)(aP + kc * 32);
        ar = __builtin_amdgcn_mfma_f32_16x16x32_f16(a, *(const f16x8*)(wR + kc * 32), ar, 0, 0, 0);
        az = __builtin_amdgcn_mfma_f32_16x16x32_f16(a, *(const f16x8*)(wZ + kc * 32), az, 0, 0, 0);
        an = __builtin_amdgcn_mfma_f32_16x16x32_f16(a, *(const f16x8*)(wN + kc * 32), an, 0, 0, 0);
      }
#pragma unroll
      for (int e = 0; e < 4; ++e) {
        int row = rh + lq * 4 + e;
        float r = 1.f / (1.f + __expf(-(ar[e] + b_r + gir[e])));
        float z = 1.f / (1.f + __expf(-(az[e] + b_z + giz[e])));
        float x2 = 2.f * (gin[e] + r * (an[e] + b_n));
        float n = 1.f - 2.f / (__expf(x2) + 1.f);   // tanh, saturates safely
        float hv = (1.f - z) * n + z * hprev[e];
        f16 hf = (f16)hv;
        h32w[row * H_ + col] = hv;
        h16w[row * H_ + col] = hf;
        hall[(size_t)(mbase + row) * H_ + col] = hf;
        int ib = lens[s * B_ + row] - 2;
        ib = ib < 0 ? 0 : (ib > TM - 1 ? TM - 1 : ib);
        if (t == ib) { c32w[row * H_ + col] = hv; c16w[row * H_ + col] = hf; }
      }
      __threadfence();
      grid.sync();
      __threadfence();
    }
  }
}

// ---------------- launcher ----------------
extern "C" void kernel_launch(void* const* d_in, const int* in_sizes, int n_in,
                              void* d_out, int out_size, void* d_ws, size_t ws_size,
                              hipStream_t stream) {
  const int*   ids   = (const int*)d_in[0];
  const int*   lens  = (const int*)d_in[1];
  const float* embed = (const float*)d_in[2];
  const float* Wih0  = (const float*)d_in[3];
  const float* Whh0  = (const float*)d_in[4];
  const float* bih0  = (const float*)d_in[5];
  const float* bhh0  = (const float*)d_in[6];
  const float* Wih1  = (const float*)d_in[7];
  const float* Whh1  = (const float*)d_in[8];
  const float* bih1  = (const float*)d_in[9];
  const float* bhh1  = (const float*)d_in[10];
  const float* Wout  = (const float*)d_in[11];
  float* out = (float*)d_out;

  char* w = (char*)d_ws;
  size_t off = 0;
  auto alloc = [&](size_t bytes) -> void* {
    void* p = w + off;
    off = (off + bytes + 255) & ~(size_t)255;
    return p;
  };
  f16*   Wih0h = (f16*)alloc((size_t)G3 * E_ * 2);
  f16*   Whh0h = (f16*)alloc((size_t)G3 * H_ * 2);
  f16*   Wih1h = (f16*)alloc((size_t)G3 * H_ * 2);
  f16*   Whh1h = (f16*)alloc((size_t)G3 * H_ * 2);
  f16*   Wouth = (f16*)alloc((size_t)V_ * H_ * 2);
  f16*   x16   = (f16*)alloc((size_t)M_ALL * E_ * 2);
  float* gib   = (float*)alloc((size_t)M_ALL * G3 * 4);   // reused: gi0 then gi1
  f16*   h0all = (f16*)alloc((size_t)M_ALL * H_ * 2);
  f16*   h1all = (f16*)alloc((size_t)M_ALL * H_ * 2);
  const size_t F32SZ = (size_t)B_ * H_ * 4;   // 128 KB
  const size_t F16SZ = (size_t)B_ * H_ * 2;   //  64 KB
  const size_t LAYER = 4 * F32SZ + 4 * F16SZ; // h32a,h32b,c32a,c32b,h16a,h16b,c16a,c16b
  char* state = (char*)alloc(2 * LAYER);

  hipMemsetAsync(state, 0, 2 * LAYER, stream);   // zeroes initial h carry (h_init = 0)

  int n4;
  n4 = G3 * E_ / 4; k_cvt<<<(n4 + 255) / 256, 256, 0, stream>>>(Wih0, Wih0h, n4);
  n4 = G3 * H_ / 4; k_cvt<<<(n4 + 255) / 256, 256, 0, stream>>>(Whh0, Whh0h, n4);
                    k_cvt<<<(n4 + 255) / 256, 256, 0, stream>>>(Wih1, Wih1h, n4);
                    k_cvt<<<(n4 + 255) / 256, 256, 0, stream>>>(Whh1, Whh1h, n4);
  n4 = V_ * H_ / 4; k_cvt<<<(n4 + 255) / 256, 256, 0, stream>>>(Wout, Wouth, n4);
  k_gather<<<M_ALL, 128, 0, stream>>>(ids, embed, x16);

  // gi0 = x @ W_ih0^T + b_ih0
  k_gemm<<<dim3(M_ALL / 128, G3 / 128), 256, 0, stream>>>(x16, Wih0h, bih0, gib, E_, G3, 0);

  // layer-0 recurrence
  {
    char* p = state;
    float* h32a = (float*)(p);              float* h32b = (float*)(p + F32SZ);
    float* c32a = (float*)(p + 2 * F32SZ);  float* c32b = (float*)(p + 3 * F32SZ);
    f16* h16a = (f16*)(p + 4 * F32SZ);          f16* h16b = (f16*)(p + 4 * F32SZ + F16SZ);
    f16* c16a = (f16*)(p + 4 * F32SZ + 2*F16SZ); f16* c16b = (f16*)(p + 4 * F32SZ + 3*F16SZ);
    void* args[] = {(void*)&Whh0h, (void*)&bhh0, (void*)&gib, (void*)&lens,
                    (void*)&h32a, (void*)&h32b, (void*)&h16a, (void*)&h16b,
                    (void*)&c32a, (void*)&c32b, (void*)&c16a, (void*)&c16b,
                    (void*)&h0all};
    hipLaunchCooperativeKernel((void*)k_rec, dim3(32), dim3(256), args, 0, stream);
  }

  // gi1 = h0_all @ W_ih1^T + b_ih1   (reuse gi buffer)
  k_gemm<<<dim3(M_ALL / 128, G3 / 128), 256, 0, stream>>>(h0all, Wih1h, bih1, gib, H_, G3, 0);

  // layer-1 recurrence
  {
    char* p = state + LAYER;
    float* h32a = (float*)(p);              float* h32b = (float*)(p + F32SZ);
    float* c32a = (float*)(p + 2 * F32SZ);  float* c32b = (float*)(p + 3 * F32SZ);
    f16* h16a = (f16*)(p + 4 * F32SZ);          f16* h16b = (f16*)(p + 4 * F32SZ + F16SZ);
    f16* c16a = (f16*)(p + 4 * F32SZ + 2*F16SZ); f16* c16b = (f16*)(p + 4 * F32SZ + 3*F16SZ);
    void* args[] = {(void*)&Whh1h, (void*)&bhh1, (void*)&gib, (void*)&lens,
                    (void*)&h32a, (void*)&h32b, (void*)&h16a, (void*)&h16b,
                    (void*)&c32a, (void*)&c32b, (void*)&c16a, (void*)&c16b,
                    (void*)&h1all};
    hipLaunchCooperativeKernel((void*)k_rec, dim3(32), dim3(256), args, 0, stream);
  }

  // logits = h1_all @ W_out^T, scattered to (s,b,t,v)
  k_gemm<<<dim3(M_ALL / 128, V_ / 128), 256, 0, stream>>>(h1all, Wouth, nullptr, out, H_, V_, 1);
}